// Round 7
// baseline (175.902 us; speedup 1.0000x reference)
//
#include <hip/hip_runtime.h>
#include <math.h>

#define NN 3072
#define NH 8
#define FO 64
#define FCAT 512
#define MAXDEG 128
#define ALPHA 0.2f

typedef __attribute__((ext_vector_type(8))) short bf16x8;
typedef __attribute__((ext_vector_type(4))) float f32x4;

static __device__ __forceinline__ unsigned short f2bf(float v) {
    union { float f; unsigned u; } x; x.f = v;
    unsigned r = x.u + 0x7fffu + ((x.u >> 16) & 1u);
    return (unsigned short)(r >> 16);
}
static __device__ __forceinline__ float bf2f(unsigned short b) {
    union { unsigned u; float f; } x; x.u = ((unsigned)b) << 16;
    return x.f;
}

// ---------------- CSR build: one wave per row, ballot-ordered (deterministic) ----------------
__global__ __launch_bounds__(64) void build_csr_k(const float* __restrict__ adj,
                                                  int* __restrict__ deg,
                                                  int* __restrict__ nbr) {
    int row = blockIdx.x;
    int lane = threadIdx.x;
    const float* arow = adj + (size_t)row * NN;
    int count = 0;
    for (int base = 0; base < NN; base += 64) {
        float v = arow[base + lane];
        unsigned long long m = __ballot(v > 0.0f);
        if (v > 0.0f) {
            int pos = count + __popcll(m & ((1ull << lane) - 1ull));
            if (pos < MAXDEG) nbr[(size_t)row * MAXDEG + pos] = base + lane;
        }
        count += __popcll(m);
    }
    if (lane == 0) deg[row] = count < MAXDEG ? count : MAXDEG;
}

// ---------------- x -> bf16 hi/lo ----------------
__global__ __launch_bounds__(256) void conv_x_k(const float* __restrict__ x,
                                                unsigned short* __restrict__ xh,
                                                unsigned short* __restrict__ xl, int n) {
    int i = blockIdx.x * 256 + threadIdx.x;
    if (i < n) {
        float v = x[i];
        unsigned short hb = f2bf(v);
        xh[i] = hb;
        xl[i] = f2bf(v - bf2f(hb));
    }
}

// ---------------- W[h][k][o] -> Wt[h][o][k] split to bf16 hi/lo ----------------
__global__ __launch_bounds__(256) void conv_wt_k(const float* __restrict__ W1,
                                                 const float* __restrict__ W2,
                                                 const float* __restrict__ W3,
                                                 const float* __restrict__ W4,
                                                 unsigned short* __restrict__ Wth,
                                                 unsigned short* __restrict__ Wtl) {
    __shared__ float t[64][65];
    int b = blockIdx.x;
    const float* W; int K; int local; size_t obase;
    if (b < 16)       { W = W1; K = 128; local = b;       obase = 0; }
    else if (b < 80)  { W = W2; K = 512; local = b - 16;  obase = 65536; }
    else if (b < 144) { W = W3; K = 512; local = b - 80;  obase = 327680; }
    else              { W = W4; K = 512; local = b - 144; obase = 589824; }
    int nkt = K >> 6;
    int h = local / nkt, kt = local - h * nkt;
    int k0 = kt * 64;
    int tid = threadIdx.x;
    for (int idx = tid; idx < 4096; idx += 256) {
        int r = idx >> 6, c = idx & 63;
        t[r][c] = W[(size_t)h * K * FO + (size_t)(k0 + r) * FO + c];
    }
    __syncthreads();
    for (int idx = tid; idx < 4096; idx += 256) {
        int o = idx >> 6, kk = idx & 63;
        float v = t[kk][o];
        unsigned short hb = f2bf(v);
        size_t dst = obase + (size_t)(h * FO + o) * K + k0 + kk;
        Wth[dst] = hb;
        Wtl[dst] = f2bf(v - bf2f(hb));
    }
}

// ---------------- split-bf16 MFMA GEMM, async global_load_lds staging, chunk-major LDS ------
// grid (NH, NN/32); block 256 = 4 waves (2 wr x 2 wc), each wave 16x32 of the 32x64 tile.
// LDS (ushort units): As_hi[0..2048) slot=(cq*32+row)*8, As_lo[2048..4096),
//                     Bs_hi[4096..8192) slot=(cq*64+col)*8, Bs_lo[8192..12288)
// Chunk-major => fragment reads are 2-way-conflict-only (free); staging dest is linear
// base + lane*16 as global_load_lds requires; no content swizzle needed.
__global__ __launch_bounds__(256) void gemm_ee_k(const unsigned short* __restrict__ Ah,
                                                 const unsigned short* __restrict__ Al,
                                                 const unsigned short* __restrict__ Bh,
                                                 const unsigned short* __restrict__ Bl,
                                                 const float* __restrict__ a,
                                                 float* __restrict__ C,
                                                 float* __restrict__ esrc,
                                                 float* __restrict__ edst, int K) {
    __shared__ __align__(16) unsigned short smem[12288];   // 24 KB
    float (*Cs)[68] = (float(*)[68])smem;                  // 32x68 f32 overlay (8704 B)

    const int tid = threadIdx.x;
    const int lane = tid & 63;
    const int wid = tid >> 6;
    const int wr = wid >> 1, wc = wid & 1;
    const int lr = lane & 15, lg = lane >> 4;
    const int h = blockIdx.x;
    const int r0 = blockIdx.y * 32;

    const unsigned short* Bhh = Bh + (size_t)h * FO * K;
    const unsigned short* Bll = Bl + (size_t)h * FO * K;

    f32x4 acc[2];
    acc[0] = (f32x4){0.f, 0.f, 0.f, 0.f};
    acc[1] = (f32x4){0.f, 0.f, 0.f, 0.f};

    for (int k0 = 0; k0 < K; k0 += 64) {
        // 24 wave-loads of 1KB each; wave w issues loads L = w, w+4, ..., w+20
        #pragma unroll
        for (int li = 0; li < 6; ++li) {
            int L = wid + 4 * li;
            unsigned short* lb;
            const unsigned short* g;
            if (L < 8) {                       // A tile: hl = L>>2, part = L&3
                int hl = L >> 2, part = L & 3;
                int slot = part * 64 + lane;   // 0..255 = cq*32+row
                int cq = slot >> 5, row = slot & 31;
                lb = smem + hl * 2048 + part * 512;
                const unsigned short* base = hl ? Al : Ah;
                g = base + (size_t)(r0 + row) * K + k0 + cq * 8;
            } else {                           // B tile: hl = (L-8)>>3, part = (L-8)&7
                int L2 = L - 8;
                int hl = L2 >> 3, part = L2 & 7;
                int slot = part * 64 + lane;   // 0..511 = cq*64+col
                int cq = slot >> 6, col = slot & 63;
                lb = smem + 4096 + hl * 4096 + part * 512;
                const unsigned short* base = hl ? Bll : Bhh;
                g = base + (size_t)col * K + k0 + cq * 8;
            }
            __builtin_amdgcn_global_load_lds(
                (const __attribute__((address_space(1))) unsigned int*)g,
                (__attribute__((address_space(3))) unsigned int*)lb, 16, 0, 0);
        }
        __syncthreads();   // compiler emits vmcnt(0) drain before barrier

        #pragma unroll
        for (int ks = 0; ks < 2; ++ks) {
            int cq = ks * 4 + lg;
            int arow = wr * 16 + lr;
            bf16x8 ah = *(const bf16x8*)&smem[(cq * 32 + arow) * 8];
            bf16x8 al = *(const bf16x8*)&smem[2048 + (cq * 32 + arow) * 8];
            bf16x8 bh[2], bl[2];
            #pragma unroll
            for (int j = 0; j < 2; ++j) {
                int col = wc * 32 + j * 16 + lr;
                bh[j] = *(const bf16x8*)&smem[4096 + (cq * 64 + col) * 8];
                bl[j] = *(const bf16x8*)&smem[8192 + (cq * 64 + col) * 8];
            }
            #pragma unroll
            for (int j = 0; j < 2; ++j) {
                acc[j] = __builtin_amdgcn_mfma_f32_16x16x32_bf16(ah, bh[j], acc[j], 0, 0, 0);
                acc[j] = __builtin_amdgcn_mfma_f32_16x16x32_bf16(ah, bl[j], acc[j], 0, 0, 0);
                acc[j] = __builtin_amdgcn_mfma_f32_16x16x32_bf16(al, bh[j], acc[j], 0, 0, 0);
            }
        }
        __syncthreads();
    }

    // stage C tile (32x64 fp32) in LDS
    #pragma unroll
    for (int j = 0; j < 2; ++j)
        #pragma unroll
        for (int r = 0; r < 4; ++r)
            Cs[wr * 16 + lg * 4 + r][wc * 32 + j * 16 + lr] = acc[j][r];
    __syncthreads();

    // coalesced float4 C stores (512 float4 over 256 threads)
    #pragma unroll
    for (int it = 0; it < 2; ++it) {
        int idx = tid + it * 256;
        int r = idx >> 4, c4 = idx & 15;
        *(float4*)&C[(size_t)(r0 + r) * FCAT + h * FO + c4 * 4] = *(float4*)&Cs[r][c4 * 4];
    }

    // fused e_src/e_dst: 8 lanes per row x 8 elems, 3-step shuffle reduce
    {
        int r = tid >> 3, sub = tid & 7;
        const float* av = a + h * 2 * FO;
        float s = 0.0f, dd = 0.0f;
        #pragma unroll
        for (int k = 0; k < 8; ++k) {
            float v = Cs[r][sub * 8 + k];
            s = fmaf(v, av[sub * 8 + k], s);
            dd = fmaf(v, av[FO + sub * 8 + k], dd);
        }
        s += __shfl_xor(s, 1); s += __shfl_xor(s, 2); s += __shfl_xor(s, 4);
        dd += __shfl_xor(dd, 1); dd += __shfl_xor(dd, 2); dd += __shfl_xor(dd, 4);
        if (sub == 0) {
            esrc[h * NN + r0 + r] = s;
            edst[h * NN + r0 + r] = dd;
        }
    }
}

// ---------------- attention + aggregation: h-major block order for L2 locality -------------
__global__ __launch_bounds__(256) void attn_agg_k(const float* __restrict__ Wh,
                                                  const float* __restrict__ esrc,
                                                  const float* __restrict__ edst,
                                                  const int* __restrict__ deg,
                                                  const int* __restrict__ nbr,
                                                  float* __restrict__ outp,
                                                  unsigned short* __restrict__ oh,
                                                  unsigned short* __restrict__ ol,
                                                  int write_f32) {
    __shared__ float pbuf[4][MAXDEG];
    __shared__ int jbuf[4][MAXDEG];
    const int ws = threadIdx.x >> 6;
    const int lane = threadIdx.x & 63;
    const int h = blockIdx.x / (NN / 4);
    const int n = (blockIdx.x % (NN / 4)) * 4 + ws;
    const int d = deg[n];
    const int* nb = nbr + (size_t)n * MAXDEG;
    const float es = esrc[h * NN + n];
    const float* ed = edst + h * NN;

    for (int t = lane; t < d; t += 64) {
        int j = nb[t];
        float e = es + ed[j];
        e = (e > 0.0f) ? e : ALPHA * e;
        jbuf[ws][t] = j;
        pbuf[ws][t] = e;
    }
    float lm = -3.0e38f;
    for (int t = lane; t < d; t += 64) lm = fmaxf(lm, pbuf[ws][t]);
    #pragma unroll
    for (int off = 32; off; off >>= 1) lm = fmaxf(lm, __shfl_xor(lm, off));
    float lsum = 0.0f;
    for (int t = lane; t < d; t += 64) {
        float pv = __expf(pbuf[ws][t] - lm);
        pbuf[ws][t] = pv;
        lsum += pv;
    }
    #pragma unroll
    for (int off = 32; off; off >>= 1) lsum += __shfl_xor(lsum, off);

    const float* whb = Wh + h * FO + lane;
    float a0 = 0.f, a1 = 0.f, a2 = 0.f, a3 = 0.f;
    int t = 0;
    for (; t + 3 < d; t += 4) {
        a0 = fmaf(pbuf[ws][t + 0], whb[(size_t)jbuf[ws][t + 0] * FCAT], a0);
        a1 = fmaf(pbuf[ws][t + 1], whb[(size_t)jbuf[ws][t + 1] * FCAT], a1);
        a2 = fmaf(pbuf[ws][t + 2], whb[(size_t)jbuf[ws][t + 2] * FCAT], a2);
        a3 = fmaf(pbuf[ws][t + 3], whb[(size_t)jbuf[ws][t + 3] * FCAT], a3);
    }
    for (; t < d; ++t)
        a0 = fmaf(pbuf[ws][t], whb[(size_t)jbuf[ws][t] * FCAT], a0);
    float acc = (a0 + a1) + (a2 + a3);
    acc /= lsum;
    float r = (acc > 0.0f) ? acc : (__expf(acc) - 1.0f);  // ELU
    size_t idx = (size_t)n * FCAT + h * FO + lane;
    if (write_f32) {
        outp[idx] = r;
    } else {
        unsigned short hb = f2bf(r);
        oh[idx] = hb;
        ol[idx] = f2bf(r - bf2f(hb));
    }
}

extern "C" void kernel_launch(void* const* d_in, const int* in_sizes, int n_in,
                              void* d_out, int out_size, void* d_ws, size_t ws_size,
                              hipStream_t stream) {
    const float* x   = (const float*)d_in[0];
    const float* adj = (const float*)d_in[1];
    const float* ap[4] = {(const float*)d_in[3], (const float*)d_in[5],
                          (const float*)d_in[7], (const float*)d_in[9]};
    float* out = (float*)d_out;

    char* p = (char*)d_ws;
    int* deg = (int*)p;              p += (size_t)NN * sizeof(int);
    int* nbr = (int*)p;              p += (size_t)NN * MAXDEG * sizeof(int);
    unsigned short* Ah = (unsigned short*)p; p += (size_t)NN * FCAT * 2;
    unsigned short* Al = (unsigned short*)p; p += (size_t)NN * FCAT * 2;
    float* WhF = (float*)p;          p += (size_t)NN * FCAT * sizeof(float);
    unsigned short* Wth = (unsigned short*)p; p += (size_t)851968 * 2;
    unsigned short* Wtl = (unsigned short*)p; p += (size_t)851968 * 2;
    float* esrc = (float*)p;         p += (size_t)NN * NH * sizeof(float);
    float* edst = (float*)p;         p += (size_t)NN * NH * sizeof(float);

    build_csr_k<<<NN, 64, 0, stream>>>(adj, deg, nbr);
    conv_x_k<<<(NN * 128 + 255) / 256, 256, 0, stream>>>(x, Ah, Al, NN * 128);
    conv_wt_k<<<208, 256, 0, stream>>>((const float*)d_in[2], (const float*)d_in[4],
                                       (const float*)d_in[6], (const float*)d_in[8],
                                       Wth, Wtl);

    const size_t woff[4] = {0, 65536, 327680, 589824};
    int K = 128;
    for (int L = 0; L < 4; ++L) {
        dim3 g(NH, NN / 32);
        gemm_ee_k<<<g, 256, 0, stream>>>(Ah, Al, Wth + woff[L], Wtl + woff[L],
                                         ap[L], WhF, esrc, edst, K);
        attn_agg_k<<<NH * (NN / 4), 256, 0, stream>>>(WhF, esrc, edst, deg, nbr,
                                                      out, Ah, Al, L == 3 ? 1 : 0);
        K = FCAT;
    }
}

// Round 8
// 143.952 us; speedup vs baseline: 1.2220x; 1.2220x over previous
//
#include <hip/hip_runtime.h>
#include <math.h>

#define NN 3072
#define NH 8
#define FO 64
#define FCAT 512
#define MAXDEG 128
#define ALPHA 0.2f

typedef __attribute__((ext_vector_type(8))) short bf16x8;
typedef __attribute__((ext_vector_type(4))) float f32x4;

static __device__ __forceinline__ unsigned short f2bf(float v) {
    union { float f; unsigned u; } x; x.f = v;
    unsigned r = x.u + 0x7fffu + ((x.u >> 16) & 1u);
    return (unsigned short)(r >> 16);
}
static __device__ __forceinline__ float bf2f(unsigned short b) {
    union { unsigned u; float f; } x; x.u = ((unsigned)b) << 16;
    return x.f;
}

// ---------------- fused prelude: conv_x (blocks 0..255) + conv_wt (0..207) + csr (256..1023) ---
__global__ __launch_bounds__(256) void prelude_k(const float* __restrict__ x,
                                                 const float* __restrict__ adj,
                                                 const float* __restrict__ W1,
                                                 const float* __restrict__ W2,
                                                 const float* __restrict__ W3,
                                                 const float* __restrict__ W4,
                                                 unsigned short* __restrict__ Ah,
                                                 unsigned short* __restrict__ Al,
                                                 unsigned short* __restrict__ Wth,
                                                 unsigned short* __restrict__ Wtl,
                                                 int* __restrict__ deg,
                                                 int* __restrict__ nbr) {
    __shared__ float t[64][65];
    const int b = blockIdx.x, tid = threadIdx.x;

    if (b < 256) {
        // conv_x: x[NN*128] -> bf16 hi/lo, 1536 elems per block
        int base = b * 1536 + tid;
        #pragma unroll
        for (int i = 0; i < 6; ++i) {
            int idx = base + i * 256;
            float v = x[idx];
            unsigned short hb = f2bf(v);
            Ah[idx] = hb;
            Al[idx] = f2bf(v - bf2f(hb));
        }
        if (b < 208) {
            // conv_wt: W[h][k][o] -> Wt[h][o][k] split hi/lo
            const float* W; int K; int local; size_t obase;
            if (b < 16)       { W = W1; K = 128; local = b;       obase = 0; }
            else if (b < 80)  { W = W2; K = 512; local = b - 16;  obase = 65536; }
            else if (b < 144) { W = W3; K = 512; local = b - 80;  obase = 327680; }
            else              { W = W4; K = 512; local = b - 144; obase = 589824; }
            int nkt = K >> 6;
            int h = local / nkt, kt = local - h * nkt;
            int k0 = kt * 64;
            for (int idx = tid; idx < 4096; idx += 256) {
                int r = idx >> 6, c = idx & 63;
                t[r][c] = W[(size_t)h * K * FO + (size_t)(k0 + r) * FO + c];
            }
            __syncthreads();
            for (int idx = tid; idx < 4096; idx += 256) {
                int o = idx >> 6, kk = idx & 63;
                float v = t[kk][o];
                unsigned short hb = f2bf(v);
                size_t dst = obase + (size_t)(h * FO + o) * K + k0 + kk;
                Wth[dst] = hb;
                Wtl[dst] = f2bf(v - bf2f(hb));
            }
        }
    } else {
        // CSR build: one wave per row, ballot-ordered
        int row = (b - 256) * 4 + (tid >> 6);
        int lane = tid & 63;
        const float* arow = adj + (size_t)row * NN;
        int count = 0;
        for (int base = 0; base < NN; base += 64) {
            float v = arow[base + lane];
            unsigned long long m = __ballot(v > 0.0f);
            if (v > 0.0f) {
                int pos = count + __popcll(m & ((1ull << lane) - 1ull));
                if (pos < MAXDEG) nbr[(size_t)row * MAXDEG + pos] = base + lane;
            }
            count += __popcll(m);
        }
        if (lane == 0) deg[row] = count < MAXDEG ? count : MAXDEG;
    }
}

// ---------------- split-bf16 MFMA GEMM (R4 structure) + VGPR prefetch of next k-tile --------
// grid (NH, NN/64); block 256 = 4 waves (2x2 of 32x32); fused parallel ee epilogue
__global__ __launch_bounds__(256) void gemm_ee_k(const unsigned short* __restrict__ Ah,
                                                 const unsigned short* __restrict__ Al,
                                                 const unsigned short* __restrict__ Bh,
                                                 const unsigned short* __restrict__ Bl,
                                                 const float* __restrict__ a,
                                                 float* __restrict__ C,
                                                 float* __restrict__ esrc,
                                                 float* __restrict__ edst, int K) {
    __shared__ __align__(16) unsigned char smem[40960];
    typedef float CsT[68];
    unsigned short* As_ = (unsigned short*)smem;            // As[2][64][80] hi/lo
    unsigned short* Bs_ = (unsigned short*)(smem + 20480);  // Bs[2][64][80]
    CsT* Cs = reinterpret_cast<CsT*>(smem);                 // overlay after main loop

    const int tid = threadIdx.x;
    const int h = blockIdx.x;
    const int r0 = blockIdx.y * 64;
    const int lane = tid & 63;
    const int wid = tid >> 6;
    const int wr = wid >> 1, wc = wid & 1;
    const int lr = lane & 15, lg = lane >> 4;

    const unsigned short* Bhh = Bh + (size_t)h * FO * K;
    const unsigned short* Bll = Bl + (size_t)h * FO * K;

    // staging indices: thread covers (row0, cq0) and (row0+32, cq0)
    const int row0 = tid >> 3, cq0 = tid & 7;
    const int off0 = row0 * 80 + ((cq0 ^ (row0 & 7)) * 8);   // (row0+32) -> off0+2560
    const size_t gA0 = (size_t)(r0 + row0) * K + cq0 * 8;
    const size_t gA1 = gA0 + (size_t)32 * K;
    const size_t gB0 = (size_t)row0 * K + cq0 * 8;
    const size_t gB1 = gB0 + (size_t)32 * K;

    bf16x8 ra0h, ra0l, ra1h, ra1l, rb0h, rb0l, rb1h, rb1l;

    auto loadg = [&](int k0) {
        ra0h = *(const bf16x8*)(Ah + gA0 + k0);
        ra0l = *(const bf16x8*)(Al + gA0 + k0);
        ra1h = *(const bf16x8*)(Ah + gA1 + k0);
        ra1l = *(const bf16x8*)(Al + gA1 + k0);
        rb0h = *(const bf16x8*)(Bhh + gB0 + k0);
        rb0l = *(const bf16x8*)(Bll + gB0 + k0);
        rb1h = *(const bf16x8*)(Bhh + gB1 + k0);
        rb1l = *(const bf16x8*)(Bll + gB1 + k0);
    };
    auto store_lds = [&]() {
        *(bf16x8*)&As_[off0] = ra0h;
        *(bf16x8*)&As_[off0 + 2560] = ra1h;
        *(bf16x8*)&As_[5120 + off0] = ra0l;
        *(bf16x8*)&As_[5120 + off0 + 2560] = ra1l;
        *(bf16x8*)&Bs_[off0] = rb0h;
        *(bf16x8*)&Bs_[off0 + 2560] = rb1h;
        *(bf16x8*)&Bs_[5120 + off0] = rb0l;
        *(bf16x8*)&Bs_[5120 + off0 + 2560] = rb1l;
    };

    f32x4 acc[2][2];
    #pragma unroll
    for (int i = 0; i < 2; ++i)
        #pragma unroll
        for (int j = 0; j < 2; ++j) acc[i][j] = (f32x4){0.f, 0.f, 0.f, 0.f};

    auto mfma_phase = [&]() {
        #pragma unroll
        for (int ks = 0; ks < 2; ++ks) {
            bf16x8 ah[2], al[2], bh[2], bl[2];
            int cq = ks * 4 + lg;
            #pragma unroll
            for (int i = 0; i < 2; ++i) {
                int row = wr * 32 + i * 16 + lr;
                int offa = row * 80 + ((cq ^ (row & 7)) * 8);
                ah[i] = *(const bf16x8*)&As_[offa];
                al[i] = *(const bf16x8*)&As_[5120 + offa];
                int col = wc * 32 + i * 16 + lr;
                int offb = col * 80 + ((cq ^ (col & 7)) * 8);
                bh[i] = *(const bf16x8*)&Bs_[offb];
                bl[i] = *(const bf16x8*)&Bs_[5120 + offb];
            }
            #pragma unroll
            for (int i = 0; i < 2; ++i)
                #pragma unroll
                for (int j = 0; j < 2; ++j) {
                    acc[i][j] = __builtin_amdgcn_mfma_f32_16x16x32_bf16(ah[i], bh[j], acc[i][j], 0, 0, 0);
                    acc[i][j] = __builtin_amdgcn_mfma_f32_16x16x32_bf16(ah[i], bl[j], acc[i][j], 0, 0, 0);
                    acc[i][j] = __builtin_amdgcn_mfma_f32_16x16x32_bf16(al[i], bh[j], acc[i][j], 0, 0, 0);
                }
        }
    };

    // prologue: stage tile 0
    loadg(0);
    store_lds();
    __syncthreads();
    // main loop: prefetch tile k0 while MFMA-ing previous tile
    for (int k0 = 64; k0 < K; k0 += 64) {
        loadg(k0);          // global loads in flight during MFMA phase
        mfma_phase();
        __syncthreads();    // all LDS reads of prev tile done
        store_lds();        // write prefetched tile (waits vmcnt as needed)
        __syncthreads();
    }
    mfma_phase();           // last tile
    __syncthreads();        // before Cs overlay

    // stage C tile in LDS (fp32)
    #pragma unroll
    for (int i = 0; i < 2; ++i)
        #pragma unroll
        for (int j = 0; j < 2; ++j)
            #pragma unroll
            for (int r = 0; r < 4; ++r)
                Cs[wr * 32 + i * 16 + lg * 4 + r][wc * 32 + j * 16 + lr] = acc[i][j][r];
    __syncthreads();

    // coalesced float4 C stores
    #pragma unroll
    for (int it = 0; it < 4; ++it) {
        int idx = tid + it * 256;
        int r = idx >> 4, c4 = idx & 15;
        *(float4*)&C[(size_t)(r0 + r) * FCAT + h * FO + c4 * 4] = *(float4*)&Cs[r][c4 * 4];
    }

    // parallel fused e_src/e_dst: 4 lanes per row, 16 elems each, 2-step shuffle reduce
    {
        int r = tid >> 2, sub = tid & 3;
        const float* av = a + h * 2 * FO;
        float s = 0.0f, dd = 0.0f;
        #pragma unroll
        for (int k = 0; k < 16; ++k) {
            float v = Cs[r][sub * 16 + k];
            s = fmaf(v, av[sub * 16 + k], s);
            dd = fmaf(v, av[FO + sub * 16 + k], dd);
        }
        s += __shfl_xor(s, 1); s += __shfl_xor(s, 2);
        dd += __shfl_xor(dd, 1); dd += __shfl_xor(dd, 2);
        if (sub == 0) {
            esrc[h * NN + r0 + r] = s;
            edst[h * NN + r0 + r] = dd;
        }
    }
}

// ---------------- attention + aggregation: h-major block order for L2 locality -------------
__global__ __launch_bounds__(256) void attn_agg_k(const float* __restrict__ Wh,
                                                  const float* __restrict__ esrc,
                                                  const float* __restrict__ edst,
                                                  const int* __restrict__ deg,
                                                  const int* __restrict__ nbr,
                                                  float* __restrict__ outp,
                                                  unsigned short* __restrict__ oh,
                                                  unsigned short* __restrict__ ol,
                                                  int write_f32) {
    __shared__ float pbuf[4][MAXDEG];
    __shared__ int jbuf[4][MAXDEG];
    const int ws = threadIdx.x >> 6;
    const int lane = threadIdx.x & 63;
    const int h = blockIdx.x / (NN / 4);
    const int n = (blockIdx.x % (NN / 4)) * 4 + ws;
    const int d = deg[n];
    const int* nb = nbr + (size_t)n * MAXDEG;
    const float es = esrc[h * NN + n];
    const float* ed = edst + h * NN;

    for (int t = lane; t < d; t += 64) {
        int j = nb[t];
        float e = es + ed[j];
        e = (e > 0.0f) ? e : ALPHA * e;
        jbuf[ws][t] = j;
        pbuf[ws][t] = e;
    }
    float lm = -3.0e38f;
    for (int t = lane; t < d; t += 64) lm = fmaxf(lm, pbuf[ws][t]);
    #pragma unroll
    for (int off = 32; off; off >>= 1) lm = fmaxf(lm, __shfl_xor(lm, off));
    float lsum = 0.0f;
    for (int t = lane; t < d; t += 64) {
        float pv = __expf(pbuf[ws][t] - lm);
        pbuf[ws][t] = pv;
        lsum += pv;
    }
    #pragma unroll
    for (int off = 32; off; off >>= 1) lsum += __shfl_xor(lsum, off);

    const float* whb = Wh + h * FO + lane;
    float a0 = 0.f, a1 = 0.f, a2 = 0.f, a3 = 0.f;
    int t = 0;
    for (; t + 3 < d; t += 4) {
        a0 = fmaf(pbuf[ws][t + 0], whb[(size_t)jbuf[ws][t + 0] * FCAT], a0);
        a1 = fmaf(pbuf[ws][t + 1], whb[(size_t)jbuf[ws][t + 1] * FCAT], a1);
        a2 = fmaf(pbuf[ws][t + 2], whb[(size_t)jbuf[ws][t + 2] * FCAT], a2);
        a3 = fmaf(pbuf[ws][t + 3], whb[(size_t)jbuf[ws][t + 3] * FCAT], a3);
    }
    for (; t < d; ++t)
        a0 = fmaf(pbuf[ws][t], whb[(size_t)jbuf[ws][t] * FCAT], a0);
    float acc = (a0 + a1) + (a2 + a3);
    acc /= lsum;
    float r = (acc > 0.0f) ? acc : (__expf(acc) - 1.0f);  // ELU
    size_t idx = (size_t)n * FCAT + h * FO + lane;
    if (write_f32) {
        outp[idx] = r;
    } else {
        unsigned short hb = f2bf(r);
        oh[idx] = hb;
        ol[idx] = f2bf(r - bf2f(hb));
    }
}

extern "C" void kernel_launch(void* const* d_in, const int* in_sizes, int n_in,
                              void* d_out, int out_size, void* d_ws, size_t ws_size,
                              hipStream_t stream) {
    const float* x   = (const float*)d_in[0];
    const float* adj = (const float*)d_in[1];
    const float* ap[4] = {(const float*)d_in[3], (const float*)d_in[5],
                          (const float*)d_in[7], (const float*)d_in[9]};
    float* out = (float*)d_out;

    char* p = (char*)d_ws;
    int* deg = (int*)p;              p += (size_t)NN * sizeof(int);
    int* nbr = (int*)p;              p += (size_t)NN * MAXDEG * sizeof(int);
    unsigned short* Ah = (unsigned short*)p; p += (size_t)NN * FCAT * 2;
    unsigned short* Al = (unsigned short*)p; p += (size_t)NN * FCAT * 2;
    float* WhF = (float*)p;          p += (size_t)NN * FCAT * sizeof(float);
    unsigned short* Wth = (unsigned short*)p; p += (size_t)851968 * 2;
    unsigned short* Wtl = (unsigned short*)p; p += (size_t)851968 * 2;
    float* esrc = (float*)p;         p += (size_t)NN * NH * sizeof(float);
    float* edst = (float*)p;         p += (size_t)NN * NH * sizeof(float);

    prelude_k<<<1024, 256, 0, stream>>>(x, adj,
                                        (const float*)d_in[2], (const float*)d_in[4],
                                        (const float*)d_in[6], (const float*)d_in[8],
                                        Ah, Al, Wth, Wtl, deg, nbr);

    const size_t woff[4] = {0, 65536, 327680, 589824};
    int K = 128;
    for (int L = 0; L < 4; ++L) {
        dim3 g(NH, NN / 64);
        gemm_ee_k<<<g, 256, 0, stream>>>(Ah, Al, Wth + woff[L], Wtl + woff[L],
                                         ap[L], WhF, esrc, edst, K);
        attn_agg_k<<<NH * (NN / 4), 256, 0, stream>>>(WhF, esrc, edst, deg, nbr,
                                                      out, Ah, Al, L == 3 ? 1 : 0);
        K = FCAT;
    }
}